// Round 12
// baseline (46.201 us; speedup 1.0000x reference)
//
#include <hip/hip_runtime.h>

// ======================= ATTRIBUTION ROUND =======================
// Kernels are byte-identical to R10. kernel_launch dispatches the roi
// kernel 3x (idempotent) to solve dur = T + 3R + gaps for R.
// =================================================================

// Problem constants (from reference)
#define OUT_H 7
#define OUT_W 7
#define NBINS 49
#define SCALE 0.0625f
#define CCH 256
#define FH 100
#define FW 100
#define FS (FH * FW)

typedef _Float16 half4 __attribute__((ext_vector_type(4)));
typedef _Float16 half8 __attribute__((ext_vector_type(8)));
typedef float f32x4 __attribute__((ext_vector_type(4)));
typedef int   i32x4 __attribute__((ext_vector_type(4)));

#define TS_S 128
#define TS_C 32

__global__ __launch_bounds__(256) void transpose_kernel(const float* __restrict__ in,
                                                        _Float16* __restrict__ out) {
    __shared__ float tile[TS_C][TS_S];  // 16 KB, swizzled columns
    const int n  = blockIdx.z;
    const int s0 = blockIdx.x * TS_S;
    const int c0 = blockIdx.y * TS_C;
    const int tid = threadIdx.x;

    const int cr = tid >> 5;         // 0..7
    const int s4 = (tid & 31) * 4;   // 0..124
#pragma unroll
    for (int it = 0; it < 4; ++it) {
        const int row = cr + it * 8;
        const int c = c0 + row;
        const int s = s0 + s4;
        f32x4 v = {0.f, 0.f, 0.f, 0.f};
        if (s < FS) v = *(const f32x4*)&in[((size_t)n * CCH + c) * FS + s];
        const int col = (s4 + 8 * it) & (TS_S - 1);   // row-group swizzle
        *(f32x4*)&tile[row][col] = v;
    }
    __syncthreads();
    const int c8p = tid & 3;
    const int c8  = c8p * 8;
    const int sr0 = tid >> 2;
#pragma unroll
    for (int it = 0; it < 2; ++it) {
        const int sr = sr0 + it * 64;
        const int s  = s0 + sr;
        if (s < FS) {
            const int col = (sr + 8 * c8p) & (TS_S - 1);
            half8 v = { (_Float16)tile[c8 + 0][col], (_Float16)tile[c8 + 1][col],
                        (_Float16)tile[c8 + 2][col], (_Float16)tile[c8 + 3][col],
                        (_Float16)tile[c8 + 4][col], (_Float16)tile[c8 + 5][col],
                        (_Float16)tile[c8 + 6][col], (_Float16)tile[c8 + 7][col] };
            *(half8*)&out[((size_t)n * FS + s) * CCH + c0 + c8] = v;
        }
    }
}

#define SLICE_CH 64

__global__ __launch_bounds__(256, 4) void roi_align_nhwc(const _Float16* __restrict__ feat,
                                                         const float* __restrict__ rois,
                                                         float* __restrict__ out) {
    const int bid   = blockIdx.x;
    const int slice = bid & 3;
    const int r     = bid >> 2;
    const int tid   = threadIdx.x;
    const int cg    = tid & 7;
    const int slot  = tid >> 3;

    __shared__ float tile[SLICE_CH * NBINS];
    __shared__ i32x4 soff[NBINS * 4];
    __shared__ half4 swt[NBINS * 4];

    const float* roi = rois + (size_t)r * 5;
    const int b = (int)roi[0];

    if (tid < NBINS * 4) {
        const int bin = tid >> 2;
        const int s   = tid & 3;
        const int iy  = s >> 1;
        const int ix  = s & 1;
        const int ph  = bin / 7;
        const int pw  = bin - ph * 7;

        const float sx = roi[1] * SCALE - 0.5f;
        const float sy = roi[2] * SCALE - 0.5f;
        const float ex = roi[3] * SCALE - 0.5f;
        const float ey = roi[4] * SCALE - 0.5f;
        const float bin_h = (ey - sy) * (1.0f / (float)OUT_H);
        const float bin_w = (ex - sx) * (1.0f / (float)OUT_W);

        float y = sy + ((float)ph + 0.25f + 0.5f * (float)iy) * bin_h;
        float x = sx + ((float)pw + 0.25f + 0.5f * (float)ix) * bin_w;
        const bool valid = (y >= -1.0f) && (y <= (float)FH) &&
                           (x >= -1.0f) && (x <= (float)FW);
        y = fminf(fmaxf(y, 0.0f), (float)(FH - 1));
        x = fminf(fmaxf(x, 0.0f), (float)(FW - 1));
        const int ylo = (int)y;
        const int xlo = (int)x;
        const int yhi = min(ylo + 1, FH - 1);
        const int xhi = min(xlo + 1, FW - 1);
        const float ly = y - (float)ylo, lx = x - (float)xlo;
        const float hy = 1.0f - ly, hx = 1.0f - lx;
        const float vm = valid ? 0.25f : 0.0f;

        i32x4 o = { (ylo * FW + xlo) * CCH, (ylo * FW + xhi) * CCH,
                    (yhi * FW + xlo) * CCH, (yhi * FW + xhi) * CCH };
        half4 w = { (_Float16)(vm * hy * hx), (_Float16)(vm * hy * lx),
                    (_Float16)(vm * ly * hx), (_Float16)(vm * ly * lx) };
        soff[tid] = o;
        swt[tid]  = w;
    }
    __syncthreads();

    const _Float16* fb = feat + ((size_t)b * FS) * CCH + (slice * SLICE_CH + cg * 8);
    const int chb = cg * 8;

#define PROCESS_BIN(BIN)                                                      \
    do {                                                                      \
        const int bin_ = (BIN);                                               \
        half8 acc = {0, 0, 0, 0, 0, 0, 0, 0};                                 \
        _Pragma("unroll")                                                     \
        for (int s_ = 0; s_ < 4; ++s_) {                                      \
            const i32x4 o = soff[bin_ * 4 + s_];                              \
            const half4 w = swt[bin_ * 4 + s_];                               \
            const half8 f00 = *(const half8*)&fb[o.x];                        \
            const half8 f01 = *(const half8*)&fb[o.y];                        \
            const half8 f10 = *(const half8*)&fb[o.z];                        \
            const half8 f11 = *(const half8*)&fb[o.w];                        \
            acc += f00 * w.x;                                                 \
            acc += f01 * w.y;                                                 \
            acc += f10 * w.z;                                                 \
            acc += f11 * w.w;                                                 \
        }                                                                     \
        _Pragma("unroll")                                                     \
        for (int k_ = 0; k_ < 8; ++k_)                                        \
            tile[(chb + k_) * NBINS + bin_] = (float)acc[k_];                 \
    } while (0)

    PROCESS_BIN(slot);
    if (slot + 32 < NBINS) {
        PROCESS_BIN(slot + 32);
    }
#undef PROCESS_BIN

    __syncthreads();
    float* outr = out + ((size_t)r * CCH + slice * SLICE_CH) * NBINS;
    const f32x4* tile4 = (const f32x4*)tile;
    f32x4* outr4 = (f32x4*)outr;
    for (int i = tid; i < (SLICE_CH * NBINS) / 4; i += 256)
        __builtin_nontemporal_store(tile4[i], &outr4[i]);
}

__global__ __launch_bounds__(256) void roi_align_nchw(const float* __restrict__ feat,
                                                      const float* __restrict__ rois,
                                                      float* __restrict__ out) {
    const int r = blockIdx.x;
    const int c = threadIdx.x;
    __shared__ float tile[CCH * NBINS];

    const float* roi = rois + (size_t)r * 5;
    const int   b  = (int)roi[0];
    const float sx = roi[1] * SCALE - 0.5f;
    const float sy = roi[2] * SCALE - 0.5f;
    const float ex = roi[3] * SCALE - 0.5f;
    const float ey = roi[4] * SCALE - 0.5f;
    const float bin_h = (ey - sy) / (float)OUT_H;
    const float bin_w = (ex - sx) / (float)OUT_W;
    const float* fb = feat + ((size_t)b * CCH + c) * FS;

    for (int bin = 0; bin < NBINS; ++bin) {
        const int ph = bin / 7, pw = bin - ph * 7;
        float acc = 0.0f;
#pragma unroll
        for (int iy = 0; iy < 2; ++iy) {
#pragma unroll
            for (int ix = 0; ix < 2; ++ix) {
                float y = sy + ((float)ph + 0.25f + 0.5f * iy) * bin_h;
                float x = sx + ((float)pw + 0.25f + 0.5f * ix) * bin_w;
                bool valid = (y >= -1.0f) && (y <= (float)FH) && (x >= -1.0f) && (x <= (float)FW);
                y = fminf(fmaxf(y, 0.0f), (float)(FH - 1));
                x = fminf(fmaxf(x, 0.0f), (float)(FW - 1));
                int ylo = (int)y, xlo = (int)x;
                int yhi = min(ylo + 1, FH - 1), xhi = min(xlo + 1, FW - 1);
                float ly = y - ylo, lx = x - xlo, hy = 1.f - ly, hx = 1.f - lx;
                if (valid)
                    acc += hy * hx * fb[ylo * FW + xlo] + hy * lx * fb[ylo * FW + xhi] +
                           ly * hx * fb[yhi * FW + xlo] + ly * lx * fb[yhi * FW + xhi];
            }
        }
        tile[c * NBINS + bin] = acc * 0.25f;
    }
    __syncthreads();
    float* outr = out + (size_t)r * CCH * NBINS;
    for (int i = c; i < CCH * NBINS; i += 256) outr[i] = tile[i];
}

extern "C" void kernel_launch(void* const* d_in, const int* in_sizes, int n_in,
                              void* d_out, int out_size, void* d_ws, size_t ws_size,
                              hipStream_t stream) {
    const float* feat = (const float*)d_in[0];
    const float* rois = (const float*)d_in[1];
    float* out = (float*)d_out;

    const int R = in_sizes[1] / 5;
    const int N = in_sizes[0] / (CCH * FS);

    const size_t need = (size_t)N * FS * CCH * sizeof(_Float16);
    if (ws_size >= need) {
        dim3 tb(256);
        dim3 tg((FS + TS_S - 1) / TS_S, CCH / TS_C, N);
        transpose_kernel<<<tg, tb, 0, stream>>>(feat, (_Float16*)d_ws);
        // ATTRIBUTION: dispatch roi 3x (idempotent). dur = T + 3R + gaps.
        roi_align_nhwc<<<R * 4, 256, 0, stream>>>((const _Float16*)d_ws, rois, out);
        roi_align_nhwc<<<R * 4, 256, 0, stream>>>((const _Float16*)d_ws, rois, out);
        roi_align_nhwc<<<R * 4, 256, 0, stream>>>((const _Float16*)d_ws, rois, out);
    } else {
        roi_align_nchw<<<R, 256, 0, stream>>>(feat, rois, out);
    }
}

// Round 13
// 29.418 us; speedup vs baseline: 1.5705x; 1.5705x over previous
//
#include <hip/hip_runtime.h>

// Problem constants (from reference)
#define OUT_H 7
#define OUT_W 7
#define NBINS 49
#define SCALE 0.0625f
#define CCH 256
#define FH 100
#define FW 100
#define FS (FH * FW)

typedef _Float16 half4 __attribute__((ext_vector_type(4)));
typedef _Float16 half8 __attribute__((ext_vector_type(8)));
typedef float f32x4 __attribute__((ext_vector_type(4)));
typedef int   i32x4 __attribute__((ext_vector_type(4)));

// ---------------------------------------------------------------------------
// Kernel 1: NCHW fp32 -> NHWC fp16 transpose, v2: full-line write ownership.
// Tile 64 ch x 64 spatial. Each block writes, per spatial position, all 64
// channels x 2B = one aligned 128B line -> no partial-line sharing across
// blocks/XCDs (the R1-R11 write-amplification bug).
// LDS swizzle col = s ^ (((c>>3)&7)<<3): read-phase f32x4 stores and
// write-phase scalar reads both <=2-way (free), 16B alignment preserved.
// fp32 reads are nontemporal (read-once; keep L2 for the fp16 NHWC map).
// ---------------------------------------------------------------------------
#define T2_C 64
#define T2_S 64

__global__ __launch_bounds__(256) void transpose_kernel(const float* __restrict__ in,
                                                        _Float16* __restrict__ out) {
    __shared__ float tile[T2_C][T2_S];  // 16 KB, swizzled columns
    const int n  = blockIdx.z;
    const int s0 = blockIdx.x * T2_S;
    const int c0 = blockIdx.y * T2_C;
    const int tid = threadIdx.x;

    // Read phase: 16-lane groups read 256B contiguous per channel row.
    const int rrow = tid >> 4;        // 0..15
    const int s4   = (tid & 15) * 4;  // 0..60
#pragma unroll
    for (int it = 0; it < 4; ++it) {
        const int row = rrow + it * 16;
        const int c = c0 + row;
        const int s = s0 + s4;
        f32x4 v = {0.f, 0.f, 0.f, 0.f};
        if (s < FS)
            v = __builtin_nontemporal_load((const f32x4*)&in[((size_t)n * CCH + c) * FS + s]);
        const int col = s4 ^ (((row >> 3) & 7) << 3);  // keeps %4 alignment
        *(f32x4*)&tile[row][col] = v;
    }
    __syncthreads();
    // Write phase: 8 lanes x half8 = one full 128B line per spatial position.
    const int cg = tid & 7;           // channel group of 8
    const int c8 = cg * 8;
#pragma unroll
    for (int it = 0; it < 2; ++it) {
        const int sl = (tid >> 3) + it * 32;  // 0..63
        const int s  = s0 + sl;
        if (s < FS) {
            // c8+k for k<8 has (c>>3)&7 == cg -> col identical across k.
            const int col = sl ^ (cg << 3);
            half8 v = { (_Float16)tile[c8 + 0][col], (_Float16)tile[c8 + 1][col],
                        (_Float16)tile[c8 + 2][col], (_Float16)tile[c8 + 3][col],
                        (_Float16)tile[c8 + 4][col], (_Float16)tile[c8 + 5][col],
                        (_Float16)tile[c8 + 6][col], (_Float16)tile[c8 + 7][col] };
            *(half8*)&out[((size_t)n * FS + s) * CCH + c0 + c8] = v;
        }
    }
}

// ---------------------------------------------------------------------------
// Kernel 2: RoIAlign on NHWC fp16 (byte-identical to R10; R ~= 10us, near
// its L2-tap + HBM-write floor per the R11 attribution).
// ---------------------------------------------------------------------------
#define SLICE_CH 64

__global__ __launch_bounds__(256, 4) void roi_align_nhwc(const _Float16* __restrict__ feat,
                                                         const float* __restrict__ rois,
                                                         float* __restrict__ out) {
    const int bid   = blockIdx.x;
    const int slice = bid & 3;
    const int r     = bid >> 2;
    const int tid   = threadIdx.x;
    const int cg    = tid & 7;
    const int slot  = tid >> 3;

    __shared__ float tile[SLICE_CH * NBINS];
    __shared__ i32x4 soff[NBINS * 4];
    __shared__ half4 swt[NBINS * 4];

    const float* roi = rois + (size_t)r * 5;
    const int b = (int)roi[0];

    if (tid < NBINS * 4) {
        const int bin = tid >> 2;
        const int s   = tid & 3;
        const int iy  = s >> 1;
        const int ix  = s & 1;
        const int ph  = bin / 7;
        const int pw  = bin - ph * 7;

        const float sx = roi[1] * SCALE - 0.5f;
        const float sy = roi[2] * SCALE - 0.5f;
        const float ex = roi[3] * SCALE - 0.5f;
        const float ey = roi[4] * SCALE - 0.5f;
        const float bin_h = (ey - sy) * (1.0f / (float)OUT_H);
        const float bin_w = (ex - sx) * (1.0f / (float)OUT_W);

        float y = sy + ((float)ph + 0.25f + 0.5f * (float)iy) * bin_h;
        float x = sx + ((float)pw + 0.25f + 0.5f * (float)ix) * bin_w;
        const bool valid = (y >= -1.0f) && (y <= (float)FH) &&
                           (x >= -1.0f) && (x <= (float)FW);
        y = fminf(fmaxf(y, 0.0f), (float)(FH - 1));
        x = fminf(fmaxf(x, 0.0f), (float)(FW - 1));
        const int ylo = (int)y;
        const int xlo = (int)x;
        const int yhi = min(ylo + 1, FH - 1);
        const int xhi = min(xlo + 1, FW - 1);
        const float ly = y - (float)ylo, lx = x - (float)xlo;
        const float hy = 1.0f - ly, hx = 1.0f - lx;
        const float vm = valid ? 0.25f : 0.0f;

        i32x4 o = { (ylo * FW + xlo) * CCH, (ylo * FW + xhi) * CCH,
                    (yhi * FW + xlo) * CCH, (yhi * FW + xhi) * CCH };
        half4 w = { (_Float16)(vm * hy * hx), (_Float16)(vm * hy * lx),
                    (_Float16)(vm * ly * hx), (_Float16)(vm * ly * lx) };
        soff[tid] = o;
        swt[tid]  = w;
    }
    __syncthreads();

    const _Float16* fb = feat + ((size_t)b * FS) * CCH + (slice * SLICE_CH + cg * 8);
    const int chb = cg * 8;

#define PROCESS_BIN(BIN)                                                      \
    do {                                                                      \
        const int bin_ = (BIN);                                               \
        half8 acc = {0, 0, 0, 0, 0, 0, 0, 0};                                 \
        _Pragma("unroll")                                                     \
        for (int s_ = 0; s_ < 4; ++s_) {                                      \
            const i32x4 o = soff[bin_ * 4 + s_];                              \
            const half4 w = swt[bin_ * 4 + s_];                               \
            const half8 f00 = *(const half8*)&fb[o.x];                        \
            const half8 f01 = *(const half8*)&fb[o.y];                        \
            const half8 f10 = *(const half8*)&fb[o.z];                        \
            const half8 f11 = *(const half8*)&fb[o.w];                        \
            acc += f00 * w.x;                                                 \
            acc += f01 * w.y;                                                 \
            acc += f10 * w.z;                                                 \
            acc += f11 * w.w;                                                 \
        }                                                                     \
        _Pragma("unroll")                                                     \
        for (int k_ = 0; k_ < 8; ++k_)                                        \
            tile[(chb + k_) * NBINS + bin_] = (float)acc[k_];                 \
    } while (0)

    PROCESS_BIN(slot);
    if (slot + 32 < NBINS) {
        PROCESS_BIN(slot + 32);
    }
#undef PROCESS_BIN

    __syncthreads();
    float* outr = out + ((size_t)r * CCH + slice * SLICE_CH) * NBINS;
    const f32x4* tile4 = (const f32x4*)tile;
    f32x4* outr4 = (f32x4*)outr;
    for (int i = tid; i < (SLICE_CH * NBINS) / 4; i += 256)
        __builtin_nontemporal_store(tile4[i], &outr4[i]);
}

// ---------------------------------------------------------------------------
// Fallback: direct NCHW fp32 kernel (used only if workspace is too small).
// ---------------------------------------------------------------------------
__global__ __launch_bounds__(256) void roi_align_nchw(const float* __restrict__ feat,
                                                      const float* __restrict__ rois,
                                                      float* __restrict__ out) {
    const int r = blockIdx.x;
    const int c = threadIdx.x;
    __shared__ float tile[CCH * NBINS];

    const float* roi = rois + (size_t)r * 5;
    const int   b  = (int)roi[0];
    const float sx = roi[1] * SCALE - 0.5f;
    const float sy = roi[2] * SCALE - 0.5f;
    const float ex = roi[3] * SCALE - 0.5f;
    const float ey = roi[4] * SCALE - 0.5f;
    const float bin_h = (ey - sy) / (float)OUT_H;
    const float bin_w = (ex - sx) / (float)OUT_W;
    const float* fb = feat + ((size_t)b * CCH + c) * FS;

    for (int bin = 0; bin < NBINS; ++bin) {
        const int ph = bin / 7, pw = bin - ph * 7;
        float acc = 0.0f;
#pragma unroll
        for (int iy = 0; iy < 2; ++iy) {
#pragma unroll
            for (int ix = 0; ix < 2; ++ix) {
                float y = sy + ((float)ph + 0.25f + 0.5f * iy) * bin_h;
                float x = sx + ((float)pw + 0.25f + 0.5f * ix) * bin_w;
                bool valid = (y >= -1.0f) && (y <= (float)FH) && (x >= -1.0f) && (x <= (float)FW);
                y = fminf(fmaxf(y, 0.0f), (float)(FH - 1));
                x = fminf(fmaxf(x, 0.0f), (float)(FW - 1));
                int ylo = (int)y, xlo = (int)x;
                int yhi = min(ylo + 1, FH - 1), xhi = min(xlo + 1, FW - 1);
                float ly = y - ylo, lx = x - xlo, hy = 1.f - ly, hx = 1.f - lx;
                if (valid)
                    acc += hy * hx * fb[ylo * FW + xlo] + hy * lx * fb[ylo * FW + xhi] +
                           ly * hx * fb[yhi * FW + xlo] + ly * lx * fb[yhi * FW + xhi];
            }
        }
        tile[c * NBINS + bin] = acc * 0.25f;
    }
    __syncthreads();
    float* outr = out + (size_t)r * CCH * NBINS;
    for (int i = c; i < CCH * NBINS; i += 256) outr[i] = tile[i];
}

extern "C" void kernel_launch(void* const* d_in, const int* in_sizes, int n_in,
                              void* d_out, int out_size, void* d_ws, size_t ws_size,
                              hipStream_t stream) {
    const float* feat = (const float*)d_in[0];
    const float* rois = (const float*)d_in[1];
    float* out = (float*)d_out;

    const int R = in_sizes[1] / 5;
    const int N = in_sizes[0] / (CCH * FS);

    const size_t need = (size_t)N * FS * CCH * sizeof(_Float16);
    if (ws_size >= need) {
        dim3 tb(256);
        dim3 tg((FS + T2_S - 1) / T2_S, CCH / T2_C, N);
        transpose_kernel<<<tg, tb, 0, stream>>>(feat, (_Float16*)d_ws);
        roi_align_nhwc<<<R * 4, 256, 0, stream>>>((const _Float16*)d_ws, rois, out);
    } else {
        roi_align_nchw<<<R, 256, 0, stream>>>(feat, rois, out);
    }
}

// Round 14
// 27.031 us; speedup vs baseline: 1.7092x; 1.0883x over previous
//
#include <hip/hip_runtime.h>

// Problem constants (from reference)
#define OUT_H 7
#define OUT_W 7
#define NBINS 49
#define SCALE 0.0625f
#define CCH 256
#define FH 100
#define FW 100
#define FS (FH * FW)

typedef _Float16 half4 __attribute__((ext_vector_type(4)));
typedef _Float16 half8 __attribute__((ext_vector_type(8)));
typedef float f32x4 __attribute__((ext_vector_type(4)));
typedef int   i32x4 __attribute__((ext_vector_type(4)));

// ---------------------------------------------------------------------------
// Kernel 1: NCHW fp32 -> NHWC fp16 transpose v3.
// Tile 64 ch x 128 spatial (32 KB LDS).
//  - Read: 32 lanes x f32x4 = 512B contiguous per channel row (plain loads).
//  - Write: 8 lanes x half8 = one FULL 128B line per spatial position
//    (no partial-line sharing across blocks/XCDs).
//  - Swizzle col' = col ^ (((row>>3)&7)<<3): read-phase stores are a
//    constant-XOR permutation (conflict-free); write-phase reads <=2-way.
// ---------------------------------------------------------------------------
#define T3_C 64
#define T3_S 128

__global__ __launch_bounds__(256) void transpose_kernel(const float* __restrict__ in,
                                                        _Float16* __restrict__ out) {
    __shared__ float tile[T3_C][T3_S];  // 32 KB, swizzled columns
    const int n  = blockIdx.z;
    const int s0 = blockIdx.x * T3_S;
    const int c0 = blockIdx.y * T3_C;
    const int tid = threadIdx.x;

    // Read phase: 512B segments; 8 rows per pass, 8 passes.
    const int r0 = tid >> 5;          // 0..7
    const int s4 = (tid & 31) * 4;    // 0..124
#pragma unroll
    for (int it = 0; it < 8; ++it) {
        const int row = r0 + it * 8;
        const int c = c0 + row;
        const int s = s0 + s4;
        f32x4 v = {0.f, 0.f, 0.f, 0.f};
        if (s < FS) v = *(const f32x4*)&in[((size_t)n * CCH + c) * FS + s];
        const int col = s4 ^ (((row >> 3) & 7) << 3);  // constant XOR per pass
        *(f32x4*)&tile[row][col] = v;
    }
    __syncthreads();
    // Write phase: full 128B line per spatial position (64ch x 2B).
    const int cg = tid & 7;           // channel group of 8
    const int c8 = cg * 8;
#pragma unroll
    for (int it = 0; it < 4; ++it) {
        const int sl = (tid >> 3) + it * 32;  // 0..127
        const int s  = s0 + sl;
        if (s < FS) {
            // rows c8..c8+7 all have (row>>3)&7 == cg -> same swizzled col.
            const int col = sl ^ (cg << 3);
            half8 v = { (_Float16)tile[c8 + 0][col], (_Float16)tile[c8 + 1][col],
                        (_Float16)tile[c8 + 2][col], (_Float16)tile[c8 + 3][col],
                        (_Float16)tile[c8 + 4][col], (_Float16)tile[c8 + 5][col],
                        (_Float16)tile[c8 + 6][col], (_Float16)tile[c8 + 7][col] };
            *(half8*)&out[((size_t)n * FS + s) * CCH + c0 + c8] = v;
        }
    }
}

// ---------------------------------------------------------------------------
// Kernel 2: RoIAlign on NHWC fp16 (byte-identical to the 26.4us R10 config;
// R ~= 8-10us, near its L2-tap + HBM-write floor per the R11 attribution).
// ---------------------------------------------------------------------------
#define SLICE_CH 64

__global__ __launch_bounds__(256, 4) void roi_align_nhwc(const _Float16* __restrict__ feat,
                                                         const float* __restrict__ rois,
                                                         float* __restrict__ out) {
    const int bid   = blockIdx.x;
    const int slice = bid & 3;
    const int r     = bid >> 2;
    const int tid   = threadIdx.x;
    const int cg    = tid & 7;
    const int slot  = tid >> 3;

    __shared__ float tile[SLICE_CH * NBINS];
    __shared__ i32x4 soff[NBINS * 4];
    __shared__ half4 swt[NBINS * 4];

    const float* roi = rois + (size_t)r * 5;
    const int b = (int)roi[0];

    if (tid < NBINS * 4) {
        const int bin = tid >> 2;
        const int s   = tid & 3;
        const int iy  = s >> 1;
        const int ix  = s & 1;
        const int ph  = bin / 7;
        const int pw  = bin - ph * 7;

        const float sx = roi[1] * SCALE - 0.5f;
        const float sy = roi[2] * SCALE - 0.5f;
        const float ex = roi[3] * SCALE - 0.5f;
        const float ey = roi[4] * SCALE - 0.5f;
        const float bin_h = (ey - sy) * (1.0f / (float)OUT_H);
        const float bin_w = (ex - sx) * (1.0f / (float)OUT_W);

        float y = sy + ((float)ph + 0.25f + 0.5f * (float)iy) * bin_h;
        float x = sx + ((float)pw + 0.25f + 0.5f * (float)ix) * bin_w;
        const bool valid = (y >= -1.0f) && (y <= (float)FH) &&
                           (x >= -1.0f) && (x <= (float)FW);
        y = fminf(fmaxf(y, 0.0f), (float)(FH - 1));
        x = fminf(fmaxf(x, 0.0f), (float)(FW - 1));
        const int ylo = (int)y;
        const int xlo = (int)x;
        const int yhi = min(ylo + 1, FH - 1);
        const int xhi = min(xlo + 1, FW - 1);
        const float ly = y - (float)ylo, lx = x - (float)xlo;
        const float hy = 1.0f - ly, hx = 1.0f - lx;
        const float vm = valid ? 0.25f : 0.0f;

        i32x4 o = { (ylo * FW + xlo) * CCH, (ylo * FW + xhi) * CCH,
                    (yhi * FW + xlo) * CCH, (yhi * FW + xhi) * CCH };
        half4 w = { (_Float16)(vm * hy * hx), (_Float16)(vm * hy * lx),
                    (_Float16)(vm * ly * hx), (_Float16)(vm * ly * lx) };
        soff[tid] = o;
        swt[tid]  = w;
    }
    __syncthreads();

    const _Float16* fb = feat + ((size_t)b * FS) * CCH + (slice * SLICE_CH + cg * 8);
    const int chb = cg * 8;

#define PROCESS_BIN(BIN)                                                      \
    do {                                                                      \
        const int bin_ = (BIN);                                               \
        half8 acc = {0, 0, 0, 0, 0, 0, 0, 0};                                 \
        _Pragma("unroll")                                                     \
        for (int s_ = 0; s_ < 4; ++s_) {                                      \
            const i32x4 o = soff[bin_ * 4 + s_];                              \
            const half4 w = swt[bin_ * 4 + s_];                               \
            const half8 f00 = *(const half8*)&fb[o.x];                        \
            const half8 f01 = *(const half8*)&fb[o.y];                        \
            const half8 f10 = *(const half8*)&fb[o.z];                        \
            const half8 f11 = *(const half8*)&fb[o.w];                        \
            acc += f00 * w.x;                                                 \
            acc += f01 * w.y;                                                 \
            acc += f10 * w.z;                                                 \
            acc += f11 * w.w;                                                 \
        }                                                                     \
        _Pragma("unroll")                                                     \
        for (int k_ = 0; k_ < 8; ++k_)                                        \
            tile[(chb + k_) * NBINS + bin_] = (float)acc[k_];                 \
    } while (0)

    PROCESS_BIN(slot);
    if (slot + 32 < NBINS) {
        PROCESS_BIN(slot + 32);
    }
#undef PROCESS_BIN

    __syncthreads();
    float* outr = out + ((size_t)r * CCH + slice * SLICE_CH) * NBINS;
    const f32x4* tile4 = (const f32x4*)tile;
    f32x4* outr4 = (f32x4*)outr;
    for (int i = tid; i < (SLICE_CH * NBINS) / 4; i += 256)
        __builtin_nontemporal_store(tile4[i], &outr4[i]);
}

// ---------------------------------------------------------------------------
// Fallback: direct NCHW fp32 kernel (used only if workspace is too small).
// ---------------------------------------------------------------------------
__global__ __launch_bounds__(256) void roi_align_nchw(const float* __restrict__ feat,
                                                      const float* __restrict__ rois,
                                                      float* __restrict__ out) {
    const int r = blockIdx.x;
    const int c = threadIdx.x;
    __shared__ float tile[CCH * NBINS];

    const float* roi = rois + (size_t)r * 5;
    const int   b  = (int)roi[0];
    const float sx = roi[1] * SCALE - 0.5f;
    const float sy = roi[2] * SCALE - 0.5f;
    const float ex = roi[3] * SCALE - 0.5f;
    const float ey = roi[4] * SCALE - 0.5f;
    const float bin_h = (ey - sy) / (float)OUT_H;
    const float bin_w = (ex - sx) / (float)OUT_W;
    const float* fb = feat + ((size_t)b * CCH + c) * FS;

    for (int bin = 0; bin < NBINS; ++bin) {
        const int ph = bin / 7, pw = bin - ph * 7;
        float acc = 0.0f;
#pragma unroll
        for (int iy = 0; iy < 2; ++iy) {
#pragma unroll
            for (int ix = 0; ix < 2; ++ix) {
                float y = sy + ((float)ph + 0.25f + 0.5f * iy) * bin_h;
                float x = sx + ((float)pw + 0.25f + 0.5f * ix) * bin_w;
                bool valid = (y >= -1.0f) && (y <= (float)FH) && (x >= -1.0f) && (x <= (float)FW);
                y = fminf(fmaxf(y, 0.0f), (float)(FH - 1));
                x = fminf(fmaxf(x, 0.0f), (float)(FW - 1));
                int ylo = (int)y, xlo = (int)x;
                int yhi = min(ylo + 1, FH - 1), xhi = min(xlo + 1, FW - 1);
                float ly = y - ylo, lx = x - xlo, hy = 1.f - ly, hx = 1.f - lx;
                if (valid)
                    acc += hy * hx * fb[ylo * FW + xlo] + hy * lx * fb[ylo * FW + xhi] +
                           ly * hx * fb[yhi * FW + xlo] + ly * lx * fb[yhi * FW + xhi];
            }
        }
        tile[c * NBINS + bin] = acc * 0.25f;
    }
    __syncthreads();
    float* outr = out + (size_t)r * CCH * NBINS;
    for (int i = c; i < CCH * NBINS; i += 256) outr[i] = tile[i];
}

extern "C" void kernel_launch(void* const* d_in, const int* in_sizes, int n_in,
                              void* d_out, int out_size, void* d_ws, size_t ws_size,
                              hipStream_t stream) {
    const float* feat = (const float*)d_in[0];
    const float* rois = (const float*)d_in[1];
    float* out = (float*)d_out;

    const int R = in_sizes[1] / 5;
    const int N = in_sizes[0] / (CCH * FS);

    const size_t need = (size_t)N * FS * CCH * sizeof(_Float16);
    if (ws_size >= need) {
        dim3 tb(256);
        dim3 tg((FS + T3_S - 1) / T3_S, CCH / T3_C, N);
        transpose_kernel<<<tg, tb, 0, stream>>>(feat, (_Float16*)d_ws);
        roi_align_nhwc<<<R * 4, 256, 0, stream>>>((const _Float16*)d_ws, rois, out);
    } else {
        roi_align_nchw<<<R, 256, 0, stream>>>(feat, rois, out);
    }
}

// Round 15
// 24.610 us; speedup vs baseline: 1.8773x; 1.0984x over previous
//
#include <hip/hip_runtime.h>

// Problem constants (from reference)
#define OUT_H 7
#define OUT_W 7
#define NBINS 49
#define SCALE 0.0625f
#define CCH 256
#define FH 100
#define FW 100
#define FS (FH * FW)

typedef _Float16 half4 __attribute__((ext_vector_type(4)));
typedef _Float16 half8 __attribute__((ext_vector_type(8)));
typedef float f32x4 __attribute__((ext_vector_type(4)));
typedef int   i32x4 __attribute__((ext_vector_type(4)));

// ---------------------------------------------------------------------------
// Kernel 1: NCHW fp32 -> NHWC fp16 transpose (R10 tile: 32ch x 128sp,
// swizzled LDS, f32x4 reads, half8 writes) with XCD-ALIGNED 1D GRID:
// bid&7 = xcdmap(c32) = (c32>>1)|((c32&1)<<2), so channel-group c32
// (roi slice s = c32>>1) is written by blocks on XCDs {s, s+4} -- the same
// XCDs whose roi blocks read it (roi: slice = bid&3 -> bid%8 in {s, s+4}).
// Dirty NHWC lines land in the reader's local L2 -> no cross-XCD handoff
// on the roi kernel's cold pass.
// ---------------------------------------------------------------------------
#define TS_S 128
#define TS_C 32

__global__ __launch_bounds__(256) void transpose_kernel(const float* __restrict__ in,
                                                        _Float16* __restrict__ out) {
    __shared__ float tile[TS_C][TS_S];  // 16 KB, swizzled columns
    const int bid = blockIdx.x;
    const int xm  = bid & 7;
    const int c32 = ((xm & 3) << 1) | (xm >> 2);  // inverse of xcdmap
    const int rest = bid >> 3;
    const int n   = rest & 1;
    const int s0  = (rest >> 1) * TS_S;
    const int c0  = c32 * TS_C;
    const int tid = threadIdx.x;

    // Read phase: lane = s-direction, f32x4 (coalesced 512B/wave).
    const int cr = tid >> 5;         // 0..7
    const int s4 = (tid & 31) * 4;   // 0..124
#pragma unroll
    for (int it = 0; it < 4; ++it) {
        const int row = cr + it * 8;
        const int c = c0 + row;
        const int s = s0 + s4;
        f32x4 v = {0.f, 0.f, 0.f, 0.f};
        if (s < FS) v = *(const f32x4*)&in[((size_t)n * CCH + c) * FS + s];
        const int col = (s4 + 8 * it) & (TS_S - 1);   // row-group swizzle
        *(f32x4*)&tile[row][col] = v;
    }
    __syncthreads();
    // Write phase: 8 channels per lane (16B stores), <=2-way bank aliasing.
    const int c8p = tid & 3;         // channel-group-of-8 index 0..3
    const int c8  = c8p * 8;
    const int sr0 = tid >> 2;        // 0..63
#pragma unroll
    for (int it = 0; it < 2; ++it) {
        const int sr = sr0 + it * 64;
        const int s  = s0 + sr;
        if (s < FS) {
            const int col = (sr + 8 * c8p) & (TS_S - 1);  // matches swizzle
            half8 v = { (_Float16)tile[c8 + 0][col], (_Float16)tile[c8 + 1][col],
                        (_Float16)tile[c8 + 2][col], (_Float16)tile[c8 + 3][col],
                        (_Float16)tile[c8 + 4][col], (_Float16)tile[c8 + 5][col],
                        (_Float16)tile[c8 + 6][col], (_Float16)tile[c8 + 7][col] };
            *(half8*)&out[((size_t)n * FS + s) * CCH + c0 + c8] = v;
        }
    }
}

// ---------------------------------------------------------------------------
// Kernel 2: RoIAlign on NHWC fp16 (byte-identical to R10's 26.4us config).
// slice = bid&3 -> bid%8 in {slice, slice+4}: reads slice s on XCDs {s,s+4},
// matching the transpose's write placement.
// ---------------------------------------------------------------------------
#define SLICE_CH 64

__global__ __launch_bounds__(256, 4) void roi_align_nhwc(const _Float16* __restrict__ feat,
                                                         const float* __restrict__ rois,
                                                         float* __restrict__ out) {
    const int bid   = blockIdx.x;
    const int slice = bid & 3;
    const int r     = bid >> 2;
    const int tid   = threadIdx.x;
    const int cg    = tid & 7;
    const int slot  = tid >> 3;

    __shared__ float tile[SLICE_CH * NBINS];
    __shared__ i32x4 soff[NBINS * 4];
    __shared__ half4 swt[NBINS * 4];

    const float* roi = rois + (size_t)r * 5;
    const int b = (int)roi[0];

    if (tid < NBINS * 4) {
        const int bin = tid >> 2;
        const int s   = tid & 3;
        const int iy  = s >> 1;
        const int ix  = s & 1;
        const int ph  = bin / 7;
        const int pw  = bin - ph * 7;

        const float sx = roi[1] * SCALE - 0.5f;
        const float sy = roi[2] * SCALE - 0.5f;
        const float ex = roi[3] * SCALE - 0.5f;
        const float ey = roi[4] * SCALE - 0.5f;
        const float bin_h = (ey - sy) * (1.0f / (float)OUT_H);
        const float bin_w = (ex - sx) * (1.0f / (float)OUT_W);

        float y = sy + ((float)ph + 0.25f + 0.5f * (float)iy) * bin_h;
        float x = sx + ((float)pw + 0.25f + 0.5f * (float)ix) * bin_w;
        const bool valid = (y >= -1.0f) && (y <= (float)FH) &&
                           (x >= -1.0f) && (x <= (float)FW);
        y = fminf(fmaxf(y, 0.0f), (float)(FH - 1));
        x = fminf(fmaxf(x, 0.0f), (float)(FW - 1));
        const int ylo = (int)y;
        const int xlo = (int)x;
        const int yhi = min(ylo + 1, FH - 1);
        const int xhi = min(xlo + 1, FW - 1);
        const float ly = y - (float)ylo, lx = x - (float)xlo;
        const float hy = 1.0f - ly, hx = 1.0f - lx;
        const float vm = valid ? 0.25f : 0.0f;

        i32x4 o = { (ylo * FW + xlo) * CCH, (ylo * FW + xhi) * CCH,
                    (yhi * FW + xlo) * CCH, (yhi * FW + xhi) * CCH };
        half4 w = { (_Float16)(vm * hy * hx), (_Float16)(vm * hy * lx),
                    (_Float16)(vm * ly * hx), (_Float16)(vm * ly * lx) };
        soff[tid] = o;
        swt[tid]  = w;
    }
    __syncthreads();

    const _Float16* fb = feat + ((size_t)b * FS) * CCH + (slice * SLICE_CH + cg * 8);
    const int chb = cg * 8;

#define PROCESS_BIN(BIN)                                                      \
    do {                                                                      \
        const int bin_ = (BIN);                                               \
        half8 acc = {0, 0, 0, 0, 0, 0, 0, 0};                                 \
        _Pragma("unroll")                                                     \
        for (int s_ = 0; s_ < 4; ++s_) {                                      \
            const i32x4 o = soff[bin_ * 4 + s_];                              \
            const half4 w = swt[bin_ * 4 + s_];                               \
            const half8 f00 = *(const half8*)&fb[o.x];                        \
            const half8 f01 = *(const half8*)&fb[o.y];                        \
            const half8 f10 = *(const half8*)&fb[o.z];                        \
            const half8 f11 = *(const half8*)&fb[o.w];                        \
            acc += f00 * w.x;                                                 \
            acc += f01 * w.y;                                                 \
            acc += f10 * w.z;                                                 \
            acc += f11 * w.w;                                                 \
        }                                                                     \
        _Pragma("unroll")                                                     \
        for (int k_ = 0; k_ < 8; ++k_)                                        \
            tile[(chb + k_) * NBINS + bin_] = (float)acc[k_];                 \
    } while (0)

    PROCESS_BIN(slot);
    if (slot + 32 < NBINS) {
        PROCESS_BIN(slot + 32);
    }
#undef PROCESS_BIN

    __syncthreads();
    float* outr = out + ((size_t)r * CCH + slice * SLICE_CH) * NBINS;
    const f32x4* tile4 = (const f32x4*)tile;
    f32x4* outr4 = (f32x4*)outr;
    for (int i = tid; i < (SLICE_CH * NBINS) / 4; i += 256)
        __builtin_nontemporal_store(tile4[i], &outr4[i]);
}

// ---------------------------------------------------------------------------
// Fallback: direct NCHW fp32 kernel (used only if workspace is too small).
// ---------------------------------------------------------------------------
__global__ __launch_bounds__(256) void roi_align_nchw(const float* __restrict__ feat,
                                                      const float* __restrict__ rois,
                                                      float* __restrict__ out) {
    const int r = blockIdx.x;
    const int c = threadIdx.x;
    __shared__ float tile[CCH * NBINS];

    const float* roi = rois + (size_t)r * 5;
    const int   b  = (int)roi[0];
    const float sx = roi[1] * SCALE - 0.5f;
    const float sy = roi[2] * SCALE - 0.5f;
    const float ex = roi[3] * SCALE - 0.5f;
    const float ey = roi[4] * SCALE - 0.5f;
    const float bin_h = (ey - sy) / (float)OUT_H;
    const float bin_w = (ex - sx) / (float)OUT_W;
    const float* fb = feat + ((size_t)b * CCH + c) * FS;

    for (int bin = 0; bin < NBINS; ++bin) {
        const int ph = bin / 7, pw = bin - ph * 7;
        float acc = 0.0f;
#pragma unroll
        for (int iy = 0; iy < 2; ++iy) {
#pragma unroll
            for (int ix = 0; ix < 2; ++ix) {
                float y = sy + ((float)ph + 0.25f + 0.5f * iy) * bin_h;
                float x = sx + ((float)pw + 0.25f + 0.5f * ix) * bin_w;
                bool valid = (y >= -1.0f) && (y <= (float)FH) && (x >= -1.0f) && (x <= (float)FW);
                y = fminf(fmaxf(y, 0.0f), (float)(FH - 1));
                x = fminf(fmaxf(x, 0.0f), (float)(FW - 1));
                int ylo = (int)y, xlo = (int)x;
                int yhi = min(ylo + 1, FH - 1), xhi = min(xlo + 1, FW - 1);
                float ly = y - ylo, lx = x - xlo, hy = 1.f - ly, hx = 1.f - lx;
                if (valid)
                    acc += hy * hx * fb[ylo * FW + xlo] + hy * lx * fb[ylo * FW + xhi] +
                           ly * hx * fb[yhi * FW + xlo] + ly * lx * fb[yhi * FW + xhi];
            }
        }
        tile[c * NBINS + bin] = acc * 0.25f;
    }
    __syncthreads();
    float* outr = out + (size_t)r * CCH * NBINS;
    for (int i = c; i < CCH * NBINS; i += 256) outr[i] = tile[i];
}

extern "C" void kernel_launch(void* const* d_in, const int* in_sizes, int n_in,
                              void* d_out, int out_size, void* d_ws, size_t ws_size,
                              hipStream_t stream) {
    const float* feat = (const float*)d_in[0];
    const float* rois = (const float*)d_in[1];
    float* out = (float*)d_out;

    const int R = in_sizes[1] / 5;
    const int N = in_sizes[0] / (CCH * FS);

    const size_t need = (size_t)N * FS * CCH * sizeof(_Float16);
    if (ws_size >= need) {
        const int nsp = (FS + TS_S - 1) / TS_S;           // 79 spatial chunks
        const int nblocks = nsp * N * 8;                  // 1D, XCD-aligned
        transpose_kernel<<<nblocks, 256, 0, stream>>>(feat, (_Float16*)d_ws);
        roi_align_nhwc<<<R * 4, 256, 0, stream>>>((const _Float16*)d_ws, rois, out);
    } else {
        roi_align_nchw<<<R, 256, 0, stream>>>(feat, rois, out);
    }
}